// Round 11
// baseline (231.409 us; speedup 1.0000x reference)
//
#include <hip/hip_runtime.h>
#include <hip/hip_bf16.h>
#include <math.h>

#define B_ 32
#define S_ 64
#define T_ 256
#define L_ 8
#define D_ 128
#define H_ 128

typedef __attribute__((ext_vector_type(8))) short short8;
typedef __attribute__((ext_vector_type(4))) short short4v;
typedef __attribute__((ext_vector_type(4))) float float4v;

__device__ __forceinline__ short f2bf(float x) {
  __hip_bfloat16 h = __float2bfloat16(x);
  return *reinterpret_cast<short*>(&h);
}

__device__ __forceinline__ float rdlane(float x, int sl) {
  return __int_as_float(__builtin_amdgcn_readlane(__float_as_int(x), sl));
}
__device__ __forceinline__ float dpp_shr1(float x, float tailv) {
  int r = __builtin_amdgcn_update_dpp(__float_as_int(tailv), __float_as_int(x),
                                      0x138, 0xF, 0xF, false);
  return __int_as_float(r);
}

// ---------------------------------------------------------------------------
// Stage A (+prep merged): blocks 0-7: Toeplitz-Schur Cholesky (readlane +
// DPP wave_shr serial chain; LDS panel flushed as coalesced rows covering
// exactly zgemm's triangular read region). Blocks 8-71: weight conversion
// W1T[h][l], W2T[c][h] (c=nt*16+n <-> d=n*8+nt); block 8 also zeroes the
// per-b completion counters used by the fused decode+LSE.
// ---------------------------------------------------------------------------
__global__ __launch_bounds__(64) void k_chol_prep(
    const float* __restrict__ times, const float* __restrict__ log_taus,
    __hip_bfloat16* __restrict__ Lcbf_,
    const float* __restrict__ W1, const float* __restrict__ W2,
    __hip_bfloat16* __restrict__ W1T, __hip_bfloat16* __restrict__ W2T,
    unsigned* __restrict__ cnt)
{
  __shared__ short panel[256][68];
  const int bi = blockIdx.x;
  const int j = threadIdx.x;

  if (bi >= 8) {
    if (bi == 8 && j < B_) cnt[j] = 0;           // zero completion counters
    const int base = (bi - 8) * 64 + j;          // 0..4095
    for (int idx = base; idx < H_ * D_; idx += 4096) {
      const int cc = idx >> 7, h = idx & 127;
      const int n = cc & 15, nt = cc >> 4;
      const int d = n * 8 + nt;
      W2T[(size_t)cc * H_ + h] = __float2bfloat16(W2[(size_t)h * D_ + d]);
    }
    for (int idx = base; idx < L_ * H_; idx += 4096) {
      const int li = idx >> 7, h = idx & 127;
      W1T[(size_t)h * L_ + li] = __float2bfloat16(W1[idx]);
    }
    return;
  }

  const int l = bi;
  short* Lbf = (short*)Lcbf_ + (size_t)l * T_ * T_;

  const float tau = expf(log_taus[l]);
  const float inv2tau2 = 0.5f / (tau * tau);
  const float sig2 = 0.999f * 0.999f;
  const float t0 = times[0];

  const float c0 = sig2 + 1e-4f;
  const float isc0 = 1.0f / sqrtf(c0);

  float u[4], v[4];
#pragma unroll
  for (int c = 0; c < 4; ++c) {
    const int d = c * 64 + j;
    const float dt = times[d] - t0;
    float cv = sig2 * __expf(-dt * dt * inv2tau2);
    if (d == 0) cv = c0;
    u[c] = cv * isc0;
    v[c] = (d == 0) ? 0.0f : u[c];
  }

#pragma unroll
  for (int p = 0; p < 4; ++p) {
    for (int kk = 0; kk < 64; ++kk) {
      const float uk = rdlane(u[p], kk);
      const float vk = rdlane(v[p], kk);
      const float rho = vk * __builtin_amdgcn_rcpf(uk);
      const float om = fmaxf(1.0f - rho * rho, 1e-12f);
      const float s = __builtin_amdgcn_rsqf(om);
      const float sr = s * rho;

      float up[4];
#pragma unroll
      for (int c = 0; c < 4; ++c) {
        if (c >= p) {
          const float uc = u[c], vc = v[c];
          up[c] = s * uc - sr * vc;
          v[c]  = s * vc - sr * uc;
          const float val = (c > p || j >= kk) ? up[c] : 0.0f;
          panel[(c - p) * 64 + j][kk] = f2bf(val);
        }
      }
#pragma unroll
      for (int c = 3; c >= 0; --c) {
        if (c >= p) {
          const float tail = (c > p) ? rdlane(up[c - 1], 63) : 0.0f;
          u[c] = dpp_shr1(up[c], tail);
        }
      }
    }
    __syncthreads();
    const int rpt = 256 - 64 * p;
    const int rsub = j >> 4, cp = (j & 15) * 4;
    for (int i0 = 0; i0 < rpt; i0 += 4) {
      const int pr = i0 + rsub;
      short4v vv = *(const short4v*)&panel[pr][cp];
      *(short4v*)&Lbf[((size_t)(p * 64 + pr) << 8) + p * 64 + cp] = vv;
    }
    __syncthreads();
  }
}

// ---------------------------------------------------------------------------
// Stage B: z GEMM via bf16 MFMA. Block = (l, bs-tile of 32) -> 512 blocks
// (2 blocks/CU: staging latency overlaps compute; L reads stay L2-resident).
// eps staged once through LDS. Wave w owns u in [64w,64w+64) => K <= 64(w+1).
// Output Z[bs][t][l] bf16.
// ---------------------------------------------------------------------------
__global__ __launch_bounds__(256) void k_zgemm(
    const float* __restrict__ eps, const __hip_bfloat16* __restrict__ Lcbf_,
    __hip_bfloat16* __restrict__ Zg)
{
  __shared__ __align__(16) short E[32][264];
  const int bi = blockIdx.x;
  const int l = bi & 7, bs0 = (bi >> 3) * 32;
  const int tid = threadIdx.x, w = tid >> 6, lane = tid & 63;
  const int n = lane & 15, q = lane >> 4;
  const short* Lb = (const short*)Lcbf_ + (size_t)l * T_ * T_;

  // stage eps[bs0+row][l][:] -> E[row][:] bf16; each thread: 32 floats
  {
    const int row = tid >> 3, seg = (tid & 7) * 32;
    const float* src = eps + ((size_t)(bs0 + row) * L_ + l) * T_ + seg;
#pragma unroll
    for (int g = 0; g < 8; ++g) {
      float4v f = *(const float4v*)(src + g * 4);
      short4v o;
#pragma unroll
      for (int jj = 0; jj < 4; ++jj) o[jj] = f2bf(f[jj]);
      *(short4v*)&E[row][seg + g * 4] = o;
    }
  }
  __syncthreads();

  float4v acc[4][2];
#pragma unroll
  for (int mt = 0; mt < 4; ++mt)
#pragma unroll
    for (int nt = 0; nt < 2; ++nt) acc[mt][nt] = (float4v){0.f, 0.f, 0.f, 0.f};

  const int kend = (w + 1) * 64;
  for (int k0 = 0; k0 < kend; k0 += 32) {
    short8 bfrg[2], afr[4];
#pragma unroll
    for (int nt = 0; nt < 2; ++nt)
      bfrg[nt] = *(const short8*)&E[nt * 16 + n][k0 + q * 8];
#pragma unroll
    for (int mt = 0; mt < 4; ++mt) {
      const int u = w * 64 + mt * 16 + n;
      afr[mt] = *(const short8*)&Lb[((size_t)u << 8) + k0 + q * 8];
    }
#pragma unroll
    for (int mt = 0; mt < 4; ++mt)
#pragma unroll
      for (int nt = 0; nt < 2; ++nt)
        acc[mt][nt] = __builtin_amdgcn_mfma_f32_16x16x32_bf16(afr[mt], bfrg[nt], acc[mt][nt], 0, 0, 0);
  }
#pragma unroll
  for (int mt = 0; mt < 4; ++mt)
#pragma unroll
    for (int nt = 0; nt < 2; ++nt) {
      const int bs = bs0 + nt * 16 + n;
#pragma unroll
      for (int r = 0; r < 4; ++r) {
        const int u = w * 64 + mt * 16 + q * 4 + r;
        Zg[((size_t)bs << 11) + (u << 3) + l] = __float2bfloat16(acc[mt][nt][r]);
      }
    }
}

// ---------------------------------------------------------------------------
// Stages C-F fused + LSE: one block per (b,s). D-columns partitioned across
// waves (2 col-tiles each); unroll 1 -> no spill at the (256,4) cap; joint
// reciprocal per tanh pair. After writing ll[bs] (agent-scope release), the
// last-finishing block of each b performs the 64-wide logsumexp -> out[b].
// ---------------------------------------------------------------------------
__global__ __launch_bounds__(256, 4) void k_decode(
    const float* __restrict__ X, const __hip_bfloat16* __restrict__ Zg,
    const __hip_bfloat16* __restrict__ W1T, const float* __restrict__ b1,
    const __hip_bfloat16* __restrict__ W2T, const float* __restrict__ b2,
    const float* __restrict__ log_R, float* __restrict__ ll,
    unsigned* __restrict__ cnt, float* __restrict__ out)
{
  __shared__ __align__(16) short Zt[256][8];
  __shared__ __align__(16) __hip_bfloat16 hS[128][136];
  __shared__ float redbuf[4];
  __shared__ int lastflag;

  const int bs = blockIdx.x;
  const int b = bs >> 6;
  const int tid = threadIdx.x;
  const int w = tid >> 6, lane = tid & 63;
  const int n = lane & 15, q = lane >> 4;
  const short* Zs = (const short*)Zg;
  const short* W1s = (const short*)W1T;
  const short* W2s = (const short*)W2T;

  *(short8*)&Zt[tid][0] = *(const short8*)&Zs[((size_t)bs << 11) + tid * 8];

  float sLR = log_R[lane] + log_R[lane + 64];
#pragma unroll
  for (int off = 32; off >= 1; off >>= 1) sLR += __shfl_xor(sLR, off);

  const int d0 = n * 8 + 2 * w;
  float invr2[2], b22[2], b12[2];
#pragma unroll
  for (int jj = 0; jj < 2; ++jj) {
    invr2[jj] = expf(-log_R[d0 + jj]);
    b22[jj] = b2[d0 + jj];
    b12[jj] = b1[(2 * w + jj) * 16 + n];
  }

  const short8 zero8 = {0, 0, 0, 0, 0, 0, 0, 0};
  short8 w1f[2];
  short8 bfr[2][4];
#pragma unroll
  for (int jj = 0; jj < 2; ++jj) {
    const int c = (2 * w + jj) * 16 + n;
    short8 v = zero8;
    if (q == 0) v = *(const short8*)&W1s[(size_t)c * L_];
    w1f[jj] = v;
#pragma unroll
    for (int ks = 0; ks < 4; ++ks)
      bfr[jj][ks] = *(const short8*)&W2s[(size_t)c * H_ + ks * 32 + q * 8];
  }

  float qsum = 0.0f;
  __syncthreads();   // Zt ready

#pragma unroll 1
  for (int half = 0; half < 2; ++half) {
#pragma unroll 1
    for (int mi = 0; mi < 8; ++mi) {
      short8 zf = zero8;
      if (q == 0) zf = *(const short8*)&Zt[half * 128 + mi * 16 + n][0];
      float4v c0 = __builtin_amdgcn_mfma_f32_16x16x32_bf16(zf, w1f[0], (float4v){0.f,0.f,0.f,0.f}, 0, 0, 0);
      float4v c1 = __builtin_amdgcn_mfma_f32_16x16x32_bf16(zf, w1f[1], (float4v){0.f,0.f,0.f,0.f}, 0, 0, 0);
#pragma unroll
      for (int r = 0; r < 4; ++r) {
        float a0 = c0[r] + b12[0];
        float a1 = c1[r] + b12[1];
        float p0 = __expf(2.f * a0) + 1.f;
        float p1 = __expf(2.f * a1) + 1.f;
        float rj = __builtin_amdgcn_rcpf(p0 * p1);
        float h0 = 1.f - 2.f * p1 * rj;
        float h1 = 1.f - 2.f * p0 * rj;
        hS[mi * 16 + q * 4 + r][(2 * w) * 16 + n] = __float2bfloat16(h0);
        hS[mi * 16 + q * 4 + r][(2 * w + 1) * 16 + n] = __float2bfloat16(h1);
      }
    }
    __syncthreads();
#pragma unroll 1
    for (int mi = 0; mi < 8; ++mi) {
      short8 af[4];
#pragma unroll
      for (int ks = 0; ks < 4; ++ks)
        af[ks] = *(const short8*)&hS[mi * 16 + n][ks * 32 + q * 8];
      float4v acc0 = (float4v){0.f, 0.f, 0.f, 0.f};
      float4v acc1 = (float4v){0.f, 0.f, 0.f, 0.f};
#pragma unroll
      for (int ks = 0; ks < 4; ++ks) {
        acc0 = __builtin_amdgcn_mfma_f32_16x16x32_bf16(af[ks], bfr[0][ks], acc0, 0, 0, 0);
        acc1 = __builtin_amdgcn_mfma_f32_16x16x32_bf16(af[ks], bfr[1][ks], acc1, 0, 0, 0);
      }
#pragma unroll
      for (int r = 0; r < 4; ++r) {
        const int t = half * 128 + mi * 16 + q * 4 + r;
        const float2 xv = *(const float2*)(X + (((size_t)b << 8) + t) * D_ + d0);
        float diff0 = xv.x - (acc0[r] + b22[0]);
        float diff1 = xv.y - (acc1[r] + b22[1]);
        qsum += diff0 * diff0 * invr2[0] + diff1 * diff1 * invr2[1];
      }
    }
    __syncthreads();
  }

#pragma unroll
  for (int off = 32; off >= 1; off >>= 1) qsum += __shfl_xor(qsum, off);
  if (lane == 0) redbuf[w] = qsum;
  __syncthreads();
  if (tid == 0) {
    float Q = redbuf[0] + redbuf[1] + redbuf[2] + redbuf[3];
    float log_norm = 0.5f * (sLR + (float)D_ * 1.8378770664093453f);
    float llv = -0.5f * Q - (float)T_ * log_norm;
    __hip_atomic_store(&ll[bs], llv, __ATOMIC_RELEASE, __HIP_MEMORY_SCOPE_AGENT);
    unsigned old = __hip_atomic_fetch_add(&cnt[b], 1u, __ATOMIC_ACQ_REL,
                                          __HIP_MEMORY_SCOPE_AGENT);
    lastflag = (old == S_ - 1) ? 1 : 0;
  }
  __syncthreads();
  if (lastflag && tid < 64) {
    float v = __hip_atomic_load(&ll[b * 64 + tid], __ATOMIC_RELAXED,
                                __HIP_MEMORY_SCOPE_AGENT);
    float m = v;
#pragma unroll
    for (int off = 32; off >= 1; off >>= 1) m = fmaxf(m, __shfl_xor(m, off));
    float e = __expf(v - m);
#pragma unroll
    for (int off = 32; off >= 1; off >>= 1) e += __shfl_xor(e, off);
    if (tid == 0) out[b] = -(m + __logf(e) - 4.1588830833596715f); // log(64)
  }
}

extern "C" void kernel_launch(void* const* d_in, const int* in_sizes, int n_in,
                              void* d_out, int out_size, void* d_ws, size_t ws_size,
                              hipStream_t stream) {
  const float* X        = (const float*)d_in[0];
  const float* times    = (const float*)d_in[1];
  const float* log_taus = (const float*)d_in[2];
  const float* log_R    = (const float*)d_in[3];
  const float* W1       = (const float*)d_in[4];
  const float* b1       = (const float*)d_in[5];
  const float* W2       = (const float*)d_in[6];
  const float* b2       = (const float*)d_in[7];
  const float* eps      = (const float*)d_in[8];
  float* out = (float*)d_out;

  char* ws = (char*)d_ws;
  __hip_bfloat16* Lcbf = (__hip_bfloat16*)(ws);                // 1 MiB bf16 [L][T][T]
  __hip_bfloat16* Zg   = (__hip_bfloat16*)(ws + 1048576);      // 8 MiB bf16 [BS][T][L]
  float* ll            = (float*)(ws + 9437184);               // 8 KiB
  __hip_bfloat16* W2T  = (__hip_bfloat16*)(ws + 9445376);      // 32 KiB
  __hip_bfloat16* W1T  = (__hip_bfloat16*)(ws + 9478144);      // 2 KiB
  unsigned* cnt        = (unsigned*)(ws + 9480192);            // 128 B

  hipLaunchKernelGGL(k_chol_prep, dim3(72),   dim3(64),  0, stream,
                     times, log_taus, Lcbf, W1, W2, W1T, W2T, cnt);
  hipLaunchKernelGGL(k_zgemm,     dim3(512),  dim3(256), 0, stream, eps, Lcbf, Zg);
  hipLaunchKernelGGL(k_decode,    dim3(2048), dim3(256), 0, stream,
                     X, Zg, W1T, b1, W2T, b2, log_R, ll, cnt, out);
}

// Round 12
// 185.596 us; speedup vs baseline: 1.2468x; 1.2468x over previous
//
#include <hip/hip_runtime.h>
#include <hip/hip_bf16.h>
#include <math.h>

#define B_ 32
#define S_ 64
#define T_ 256
#define L_ 8
#define D_ 128
#define H_ 128

typedef __attribute__((ext_vector_type(8))) short short8;
typedef __attribute__((ext_vector_type(4))) short short4v;
typedef __attribute__((ext_vector_type(4))) float float4v;

__device__ __forceinline__ short f2bf(float x) {
  __hip_bfloat16 h = __float2bfloat16(x);
  return *reinterpret_cast<short*>(&h);
}

__device__ __forceinline__ float rdlane(float x, int sl) {
  return __int_as_float(__builtin_amdgcn_readlane(__float_as_int(x), sl));
}
__device__ __forceinline__ float dpp_shr1(float x, float tailv) {
  int r = __builtin_amdgcn_update_dpp(__float_as_int(tailv), __float_as_int(x),
                                      0x138, 0xF, 0xF, false);
  return __int_as_float(r);
}

// ---------------------------------------------------------------------------
// Stage A (+prep merged): blocks 0-7: Toeplitz-Schur Cholesky (readlane +
// DPP wave_shr serial chain; LDS panel flushed as coalesced rows covering
// exactly zgemm's triangular read region). Blocks 8-71: weight conversion
// W1T[h][l], W2T[c][h] (c=nt*16+n <-> d=n*8+nt).
// ---------------------------------------------------------------------------
__global__ __launch_bounds__(64) void k_chol_prep(
    const float* __restrict__ times, const float* __restrict__ log_taus,
    __hip_bfloat16* __restrict__ Lcbf_,
    const float* __restrict__ W1, const float* __restrict__ W2,
    __hip_bfloat16* __restrict__ W1T, __hip_bfloat16* __restrict__ W2T)
{
  __shared__ short panel[256][68];
  const int bi = blockIdx.x;
  const int j = threadIdx.x;

  if (bi >= 8) {
    const int base = (bi - 8) * 64 + j;          // 0..4095
    for (int idx = base; idx < H_ * D_; idx += 4096) {
      const int cc = idx >> 7, h = idx & 127;
      const int n = cc & 15, nt = cc >> 4;
      const int d = n * 8 + nt;
      W2T[(size_t)cc * H_ + h] = __float2bfloat16(W2[(size_t)h * D_ + d]);
    }
    for (int idx = base; idx < L_ * H_; idx += 4096) {
      const int li = idx >> 7, h = idx & 127;
      W1T[(size_t)h * L_ + li] = __float2bfloat16(W1[idx]);
    }
    return;
  }

  const int l = bi;
  short* Lbf = (short*)Lcbf_ + (size_t)l * T_ * T_;

  const float tau = expf(log_taus[l]);
  const float inv2tau2 = 0.5f / (tau * tau);
  const float sig2 = 0.999f * 0.999f;
  const float t0 = times[0];

  const float c0 = sig2 + 1e-4f;
  const float isc0 = 1.0f / sqrtf(c0);

  float u[4], v[4];
#pragma unroll
  for (int c = 0; c < 4; ++c) {
    const int d = c * 64 + j;
    const float dt = times[d] - t0;
    float cv = sig2 * __expf(-dt * dt * inv2tau2);
    if (d == 0) cv = c0;
    u[c] = cv * isc0;
    v[c] = (d == 0) ? 0.0f : u[c];
  }

#pragma unroll
  for (int p = 0; p < 4; ++p) {
    for (int kk = 0; kk < 64; ++kk) {
      const float uk = rdlane(u[p], kk);
      const float vk = rdlane(v[p], kk);
      const float rho = vk * __builtin_amdgcn_rcpf(uk);
      const float om = fmaxf(1.0f - rho * rho, 1e-12f);
      const float s = __builtin_amdgcn_rsqf(om);
      const float sr = s * rho;

      float up[4];
#pragma unroll
      for (int c = 0; c < 4; ++c) {
        if (c >= p) {
          const float uc = u[c], vc = v[c];
          up[c] = s * uc - sr * vc;
          v[c]  = s * vc - sr * uc;
          const float val = (c > p || j >= kk) ? up[c] : 0.0f;
          panel[(c - p) * 64 + j][kk] = f2bf(val);
        }
      }
#pragma unroll
      for (int c = 3; c >= 0; --c) {
        if (c >= p) {
          const float tail = (c > p) ? rdlane(up[c - 1], 63) : 0.0f;
          u[c] = dpp_shr1(up[c], tail);
        }
      }
    }
    __syncthreads();
    const int rpt = 256 - 64 * p;
    const int rsub = j >> 4, cp = (j & 15) * 4;
    for (int i0 = 0; i0 < rpt; i0 += 4) {
      const int pr = i0 + rsub;
      short4v vv = *(const short4v*)&panel[pr][cp];
      *(short4v*)&Lbf[((size_t)(p * 64 + pr) << 8) + p * 64 + cp] = vv;
    }
    __syncthreads();
  }
}

// ---------------------------------------------------------------------------
// Stage B: z GEMM via bf16 MFMA. Block = (l, u-half, bs-tile of 64) -> 512
// blocks (>=2 blocks/CU so staging latency overlaps compute; 64-wide eps
// tiles keep the L-read amortization that won R10). Wave w owns u in
// [uh*128 + 32w, uh*128 + 32w + 32) => kend = uh*128 + 32w + 32 (triangular
// skip). eps staged once through LDS. Output Z[bs][t][l] bf16.
// ---------------------------------------------------------------------------
__global__ __launch_bounds__(256) void k_zgemm(
    const float* __restrict__ eps, const __hip_bfloat16* __restrict__ Lcbf_,
    __hip_bfloat16* __restrict__ Zg)
{
  __shared__ __align__(16) short E[64][264];
  const int bi = blockIdx.x;
  const int l = bi & 7, uh = (bi >> 3) & 1, bs0 = (bi >> 4) * 64;
  const int tid = threadIdx.x, w = tid >> 6, lane = tid & 63;
  const int n = lane & 15, q = lane >> 4;
  const short* Lb = (const short*)Lcbf_ + (size_t)l * T_ * T_;

  const int u0 = uh * 128 + w * 32;
  const int kend = u0 + 32;

  // stage eps[bs0+row][l][0:kend_max] -> E[row][:]; each thread covers its
  // segment (only k < uh*128+128 is ever read; stage full row for simplicity)
  {
    const int row = tid >> 2, seg = (tid & 3) * 64;
    const float* src = eps + ((size_t)(bs0 + row) * L_ + l) * T_ + seg;
#pragma unroll
    for (int g = 0; g < 16; ++g) {
      float4v f = *(const float4v*)(src + g * 4);
      short4v o;
#pragma unroll
      for (int jj = 0; jj < 4; ++jj) o[jj] = f2bf(f[jj]);
      *(short4v*)&E[row][seg + g * 4] = o;
    }
  }
  __syncthreads();

  float4v acc[2][4];
#pragma unroll
  for (int mt = 0; mt < 2; ++mt)
#pragma unroll
    for (int nt = 0; nt < 4; ++nt) acc[mt][nt] = (float4v){0.f, 0.f, 0.f, 0.f};

  for (int k0 = 0; k0 < kend; k0 += 32) {
    short8 bfrg[4], afr[2];
#pragma unroll
    for (int nt = 0; nt < 4; ++nt)
      bfrg[nt] = *(const short8*)&E[nt * 16 + n][k0 + q * 8];
#pragma unroll
    for (int mt = 0; mt < 2; ++mt) {
      const int u = u0 + mt * 16 + n;
      afr[mt] = *(const short8*)&Lb[((size_t)u << 8) + k0 + q * 8];
    }
#pragma unroll
    for (int mt = 0; mt < 2; ++mt)
#pragma unroll
      for (int nt = 0; nt < 4; ++nt)
        acc[mt][nt] = __builtin_amdgcn_mfma_f32_16x16x32_bf16(afr[mt], bfrg[nt], acc[mt][nt], 0, 0, 0);
  }
#pragma unroll
  for (int mt = 0; mt < 2; ++mt)
#pragma unroll
    for (int nt = 0; nt < 4; ++nt) {
      const int bs = bs0 + nt * 16 + n;
#pragma unroll
      for (int r = 0; r < 4; ++r) {
        const int u = u0 + mt * 16 + q * 4 + r;
        Zg[((size_t)bs << 11) + (u << 3) + l] = __float2bfloat16(acc[mt][nt][r]);
      }
    }
}

// ---------------------------------------------------------------------------
// Stages C-F fused: one block per (b,s). D-columns partitioned across waves
// (2 col-tiles each); T processed in QUARTERS of 64 rows so hS is 17.4 KB ->
// ~6-7 blocks/CU at launch_bounds (256,6) (VGPR cap 85 >> 52 used, no
// spill). unroll 1 on the t loops; joint reciprocal per tanh pair.
// ---------------------------------------------------------------------------
__global__ __launch_bounds__(256, 6) void k_decode(
    const float* __restrict__ X, const __hip_bfloat16* __restrict__ Zg,
    const __hip_bfloat16* __restrict__ W1T, const float* __restrict__ b1,
    const __hip_bfloat16* __restrict__ W2T, const float* __restrict__ b2,
    const float* __restrict__ log_R, float* __restrict__ ll)
{
  __shared__ __align__(16) short Zt[256][8];
  __shared__ __align__(16) __hip_bfloat16 hS[64][136];
  __shared__ float redbuf[4];

  const int bs = blockIdx.x;
  const int b = bs >> 6;
  const int tid = threadIdx.x;
  const int w = tid >> 6, lane = tid & 63;
  const int n = lane & 15, q = lane >> 4;
  const short* Zs = (const short*)Zg;
  const short* W1s = (const short*)W1T;
  const short* W2s = (const short*)W2T;

  *(short8*)&Zt[tid][0] = *(const short8*)&Zs[((size_t)bs << 11) + tid * 8];

  float sLR = log_R[lane] + log_R[lane + 64];
#pragma unroll
  for (int off = 32; off >= 1; off >>= 1) sLR += __shfl_xor(sLR, off);

  const int d0 = n * 8 + 2 * w;
  float invr2[2], b22[2], b12[2];
#pragma unroll
  for (int jj = 0; jj < 2; ++jj) {
    invr2[jj] = expf(-log_R[d0 + jj]);
    b22[jj] = b2[d0 + jj];
    b12[jj] = b1[(2 * w + jj) * 16 + n];
  }

  const short8 zero8 = {0, 0, 0, 0, 0, 0, 0, 0};
  short8 w1f[2];
  short8 bfr[2][4];
#pragma unroll
  for (int jj = 0; jj < 2; ++jj) {
    const int c = (2 * w + jj) * 16 + n;
    short8 v = zero8;
    if (q == 0) v = *(const short8*)&W1s[(size_t)c * L_];
    w1f[jj] = v;
#pragma unroll
    for (int ks = 0; ks < 4; ++ks)
      bfr[jj][ks] = *(const short8*)&W2s[(size_t)c * H_ + ks * 32 + q * 8];
  }

  float qsum = 0.0f;
  __syncthreads();   // Zt ready

#pragma unroll 1
  for (int qt = 0; qt < 4; ++qt) {
    // --- h-phase: 64 rows of this quarter, wave's 32 cols ---
#pragma unroll 1
    for (int mi = 0; mi < 4; ++mi) {
      short8 zf = zero8;
      if (q == 0) zf = *(const short8*)&Zt[qt * 64 + mi * 16 + n][0];
      float4v c0 = __builtin_amdgcn_mfma_f32_16x16x32_bf16(zf, w1f[0], (float4v){0.f,0.f,0.f,0.f}, 0, 0, 0);
      float4v c1 = __builtin_amdgcn_mfma_f32_16x16x32_bf16(zf, w1f[1], (float4v){0.f,0.f,0.f,0.f}, 0, 0, 0);
#pragma unroll
      for (int r = 0; r < 4; ++r) {
        float a0 = c0[r] + b12[0];
        float a1 = c1[r] + b12[1];
        float p0 = __expf(2.f * a0) + 1.f;
        float p1 = __expf(2.f * a1) + 1.f;
        float rj = __builtin_amdgcn_rcpf(p0 * p1);
        float h0 = 1.f - 2.f * p1 * rj;
        float h1 = 1.f - 2.f * p0 * rj;
        hS[mi * 16 + q * 4 + r][(2 * w) * 16 + n] = __float2bfloat16(h0);
        hS[mi * 16 + q * 4 + r][(2 * w + 1) * 16 + n] = __float2bfloat16(h1);
      }
    }
    __syncthreads();
    // --- mu-phase + epilogue: wave's 2 col-tiles, this quarter's rows ---
#pragma unroll 1
    for (int mi = 0; mi < 4; ++mi) {
      short8 af[4];
#pragma unroll
      for (int ks = 0; ks < 4; ++ks)
        af[ks] = *(const short8*)&hS[mi * 16 + n][ks * 32 + q * 8];
      float4v acc0 = (float4v){0.f, 0.f, 0.f, 0.f};
      float4v acc1 = (float4v){0.f, 0.f, 0.f, 0.f};
#pragma unroll
      for (int ks = 0; ks < 4; ++ks) {
        acc0 = __builtin_amdgcn_mfma_f32_16x16x32_bf16(af[ks], bfr[0][ks], acc0, 0, 0, 0);
        acc1 = __builtin_amdgcn_mfma_f32_16x16x32_bf16(af[ks], bfr[1][ks], acc1, 0, 0, 0);
      }
#pragma unroll
      for (int r = 0; r < 4; ++r) {
        const int t = qt * 64 + mi * 16 + q * 4 + r;
        const float2 xv = *(const float2*)(X + (((size_t)b << 8) + t) * D_ + d0);
        float diff0 = xv.x - (acc0[r] + b22[0]);
        float diff1 = xv.y - (acc1[r] + b22[1]);
        qsum += diff0 * diff0 * invr2[0] + diff1 * diff1 * invr2[1];
      }
    }
    __syncthreads();
  }

#pragma unroll
  for (int off = 32; off >= 1; off >>= 1) qsum += __shfl_xor(qsum, off);
  if (lane == 0) redbuf[w] = qsum;
  __syncthreads();
  if (tid == 0) {
    float Q = redbuf[0] + redbuf[1] + redbuf[2] + redbuf[3];
    float log_norm = 0.5f * (sLR + (float)D_ * 1.8378770664093453f);
    ll[bs] = -0.5f * Q - (float)T_ * log_norm;
  }
}

// ---------------------------------------------------------------------------
// Final: nll[b] = -(logsumexp_s(ll) - log S). One wave per b.
// ---------------------------------------------------------------------------
__global__ __launch_bounds__(64) void k_lse(
    const float* __restrict__ ll, float* __restrict__ out)
{
  const int b = blockIdx.x;
  const int s = threadIdx.x;
  float v = ll[b * 64 + s];
  float m = v;
#pragma unroll
  for (int off = 32; off >= 1; off >>= 1) m = fmaxf(m, __shfl_xor(m, off));
  float e = __expf(v - m);
#pragma unroll
  for (int off = 32; off >= 1; off >>= 1) e += __shfl_xor(e, off);
  if (s == 0) out[b] = -(m + __logf(e) - 4.1588830833596715f);
}

extern "C" void kernel_launch(void* const* d_in, const int* in_sizes, int n_in,
                              void* d_out, int out_size, void* d_ws, size_t ws_size,
                              hipStream_t stream) {
  const float* X        = (const float*)d_in[0];
  const float* times    = (const float*)d_in[1];
  const float* log_taus = (const float*)d_in[2];
  const float* log_R    = (const float*)d_in[3];
  const float* W1       = (const float*)d_in[4];
  const float* b1       = (const float*)d_in[5];
  const float* W2       = (const float*)d_in[6];
  const float* b2       = (const float*)d_in[7];
  const float* eps      = (const float*)d_in[8];
  float* out = (float*)d_out;

  char* ws = (char*)d_ws;
  __hip_bfloat16* Lcbf = (__hip_bfloat16*)(ws);                // 1 MiB bf16 [L][T][T]
  __hip_bfloat16* Zg   = (__hip_bfloat16*)(ws + 1048576);      // 8 MiB bf16 [BS][T][L]
  float* ll            = (float*)(ws + 9437184);               // 8 KiB
  __hip_bfloat16* W2T  = (__hip_bfloat16*)(ws + 9445376);      // 32 KiB
  __hip_bfloat16* W1T  = (__hip_bfloat16*)(ws + 9478144);      // 2 KiB

  hipLaunchKernelGGL(k_chol_prep, dim3(72),   dim3(64),  0, stream,
                     times, log_taus, Lcbf, W1, W2, W1T, W2T);
  hipLaunchKernelGGL(k_zgemm,     dim3(512),  dim3(256), 0, stream, eps, Lcbf, Zg);
  hipLaunchKernelGGL(k_decode,    dim3(2048), dim3(256), 0, stream,
                     X, Zg, W1T, b1, W2T, b2, log_R, ll);
  hipLaunchKernelGGL(k_lse,       dim3(32),   dim3(64),  0, stream, ll, out);
}

// Round 13
// 176.111 us; speedup vs baseline: 1.3140x; 1.0539x over previous
//
#include <hip/hip_runtime.h>
#include <hip/hip_bf16.h>
#include <math.h>

#define B_ 32
#define S_ 64
#define T_ 256
#define L_ 8
#define D_ 128
#define H_ 128

typedef __attribute__((ext_vector_type(8))) short short8;
typedef __attribute__((ext_vector_type(4))) short short4v;
typedef __attribute__((ext_vector_type(4))) float float4v;

__device__ __forceinline__ short f2bf(float x) {
  __hip_bfloat16 h = __float2bfloat16(x);
  return *reinterpret_cast<short*>(&h);
}

__device__ __forceinline__ float rdlane(float x, int sl) {
  return __int_as_float(__builtin_amdgcn_readlane(__float_as_int(x), sl));
}
__device__ __forceinline__ float dpp_shr1(float x, float tailv) {
  int r = __builtin_amdgcn_update_dpp(__float_as_int(tailv), __float_as_int(x),
                                      0x138, 0xF, 0xF, false);
  return __int_as_float(r);
}

// ---------------------------------------------------------------------------
// Stage A (+prep merged): blocks 0-7: Toeplitz-Schur Cholesky (readlane +
// DPP wave_shr serial chain; LDS panel flushed as coalesced rows covering
// exactly zgemm's triangular read region). Blocks 8-71: weight conversion
// W1T[h][l], W2T[c][h] (c=nt*16+n <-> d=n*8+nt).
// ---------------------------------------------------------------------------
__global__ __launch_bounds__(64) void k_chol_prep(
    const float* __restrict__ times, const float* __restrict__ log_taus,
    __hip_bfloat16* __restrict__ Lcbf_,
    const float* __restrict__ W1, const float* __restrict__ W2,
    __hip_bfloat16* __restrict__ W1T, __hip_bfloat16* __restrict__ W2T)
{
  __shared__ short panel[256][68];
  const int bi = blockIdx.x;
  const int j = threadIdx.x;

  if (bi >= 8) {
    const int base = (bi - 8) * 64 + j;          // 0..4095
    for (int idx = base; idx < H_ * D_; idx += 4096) {
      const int cc = idx >> 7, h = idx & 127;
      const int n = cc & 15, nt = cc >> 4;
      const int d = n * 8 + nt;
      W2T[(size_t)cc * H_ + h] = __float2bfloat16(W2[(size_t)h * D_ + d]);
    }
    for (int idx = base; idx < L_ * H_; idx += 4096) {
      const int li = idx >> 7, h = idx & 127;
      W1T[(size_t)h * L_ + li] = __float2bfloat16(W1[idx]);
    }
    return;
  }

  const int l = bi;
  short* Lbf = (short*)Lcbf_ + (size_t)l * T_ * T_;

  const float tau = expf(log_taus[l]);
  const float inv2tau2 = 0.5f / (tau * tau);
  const float sig2 = 0.999f * 0.999f;
  const float t0 = times[0];

  const float c0 = sig2 + 1e-4f;
  const float isc0 = 1.0f / sqrtf(c0);

  float u[4], v[4];
#pragma unroll
  for (int c = 0; c < 4; ++c) {
    const int d = c * 64 + j;
    const float dt = times[d] - t0;
    float cv = sig2 * __expf(-dt * dt * inv2tau2);
    if (d == 0) cv = c0;
    u[c] = cv * isc0;
    v[c] = (d == 0) ? 0.0f : u[c];
  }

#pragma unroll
  for (int p = 0; p < 4; ++p) {
    for (int kk = 0; kk < 64; ++kk) {
      const float uk = rdlane(u[p], kk);
      const float vk = rdlane(v[p], kk);
      const float rho = vk * __builtin_amdgcn_rcpf(uk);
      const float om = fmaxf(1.0f - rho * rho, 1e-12f);
      const float s = __builtin_amdgcn_rsqf(om);
      const float sr = s * rho;

      float up[4];
#pragma unroll
      for (int c = 0; c < 4; ++c) {
        if (c >= p) {
          const float uc = u[c], vc = v[c];
          up[c] = s * uc - sr * vc;
          v[c]  = s * vc - sr * uc;
          const float val = (c > p || j >= kk) ? up[c] : 0.0f;
          panel[(c - p) * 64 + j][kk] = f2bf(val);
        }
      }
#pragma unroll
      for (int c = 3; c >= 0; --c) {
        if (c >= p) {
          const float tail = (c > p) ? rdlane(up[c - 1], 63) : 0.0f;
          u[c] = dpp_shr1(up[c], tail);
        }
      }
    }
    __syncthreads();
    const int rpt = 256 - 64 * p;
    const int rsub = j >> 4, cp = (j & 15) * 4;
    for (int i0 = 0; i0 < rpt; i0 += 4) {
      const int pr = i0 + rsub;
      short4v vv = *(const short4v*)&panel[pr][cp];
      *(short4v*)&Lbf[((size_t)(p * 64 + pr) << 8) + p * 64 + cp] = vv;
    }
    __syncthreads();
  }
}

// ---------------------------------------------------------------------------
// Stage B: z GEMM via bf16 MFMA. Block = (l, u-half, bs-tile of 64) -> 512
// blocks (2 blocks/CU so staging latency overlaps compute; 64-wide eps tiles
// keep the R10 L-read amortization). Wave w owns u in [uh*128+32w, +32) =>
// kend = uh*128+32w+32 (triangular skip). Output Z[bs][t][l] bf16.
// ---------------------------------------------------------------------------
__global__ __launch_bounds__(256) void k_zgemm(
    const float* __restrict__ eps, const __hip_bfloat16* __restrict__ Lcbf_,
    __hip_bfloat16* __restrict__ Zg)
{
  __shared__ __align__(16) short E[64][264];
  const int bi = blockIdx.x;
  const int l = bi & 7, uh = (bi >> 3) & 1, bs0 = (bi >> 4) * 64;
  const int tid = threadIdx.x, w = tid >> 6, lane = tid & 63;
  const int n = lane & 15, q = lane >> 4;
  const short* Lb = (const short*)Lcbf_ + (size_t)l * T_ * T_;

  const int u0 = uh * 128 + w * 32;
  const int kend = u0 + 32;

  {
    const int row = tid >> 2, seg = (tid & 3) * 64;
    const float* src = eps + ((size_t)(bs0 + row) * L_ + l) * T_ + seg;
#pragma unroll
    for (int g = 0; g < 16; ++g) {
      float4v f = *(const float4v*)(src + g * 4);
      short4v o;
#pragma unroll
      for (int jj = 0; jj < 4; ++jj) o[jj] = f2bf(f[jj]);
      *(short4v*)&E[row][seg + g * 4] = o;
    }
  }
  __syncthreads();

  float4v acc[2][4];
#pragma unroll
  for (int mt = 0; mt < 2; ++mt)
#pragma unroll
    for (int nt = 0; nt < 4; ++nt) acc[mt][nt] = (float4v){0.f, 0.f, 0.f, 0.f};

  for (int k0 = 0; k0 < kend; k0 += 32) {
    short8 bfrg[4], afr[2];
#pragma unroll
    for (int nt = 0; nt < 4; ++nt)
      bfrg[nt] = *(const short8*)&E[nt * 16 + n][k0 + q * 8];
#pragma unroll
    for (int mt = 0; mt < 2; ++mt) {
      const int u = u0 + mt * 16 + n;
      afr[mt] = *(const short8*)&Lb[((size_t)u << 8) + k0 + q * 8];
    }
#pragma unroll
    for (int mt = 0; mt < 2; ++mt)
#pragma unroll
      for (int nt = 0; nt < 4; ++nt)
        acc[mt][nt] = __builtin_amdgcn_mfma_f32_16x16x32_bf16(afr[mt], bfrg[nt], acc[mt][nt], 0, 0, 0);
  }
#pragma unroll
  for (int mt = 0; mt < 2; ++mt)
#pragma unroll
    for (int nt = 0; nt < 4; ++nt) {
      const int bs = bs0 + nt * 16 + n;
#pragma unroll
      for (int r = 0; r < 4; ++r) {
        const int u = u0 + mt * 16 + q * 4 + r;
        Zg[((size_t)bs << 11) + (u << 3) + l] = __float2bfloat16(acc[mt][nt][r]);
      }
    }
}

// ---------------------------------------------------------------------------
// Stages C-F fused — EXACT R10 champion: one block per (b,s), D-columns
// partitioned across waves (2 col-tiles each), hS[128][136] halves,
// launch_bounds (256,4), unroll 1 (no spill; WRITE must stay ~64 KB),
// joint reciprocal per tanh pair.
// ---------------------------------------------------------------------------
__global__ __launch_bounds__(256, 4) void k_decode(
    const float* __restrict__ X, const __hip_bfloat16* __restrict__ Zg,
    const __hip_bfloat16* __restrict__ W1T, const float* __restrict__ b1,
    const __hip_bfloat16* __restrict__ W2T, const float* __restrict__ b2,
    const float* __restrict__ log_R, float* __restrict__ ll)
{
  __shared__ __align__(16) short Zt[256][8];
  __shared__ __align__(16) __hip_bfloat16 hS[128][136];
  __shared__ float redbuf[4];

  const int bs = blockIdx.x;
  const int b = bs >> 6;
  const int tid = threadIdx.x;
  const int w = tid >> 6, lane = tid & 63;
  const int n = lane & 15, q = lane >> 4;
  const short* Zs = (const short*)Zg;
  const short* W1s = (const short*)W1T;
  const short* W2s = (const short*)W2T;

  *(short8*)&Zt[tid][0] = *(const short8*)&Zs[((size_t)bs << 11) + tid * 8];

  float sLR = log_R[lane] + log_R[lane + 64];
#pragma unroll
  for (int off = 32; off >= 1; off >>= 1) sLR += __shfl_xor(sLR, off);

  const int d0 = n * 8 + 2 * w;
  float invr2[2], b22[2], b12[2];
#pragma unroll
  for (int jj = 0; jj < 2; ++jj) {
    invr2[jj] = expf(-log_R[d0 + jj]);
    b22[jj] = b2[d0 + jj];
    b12[jj] = b1[(2 * w + jj) * 16 + n];
  }

  const short8 zero8 = {0, 0, 0, 0, 0, 0, 0, 0};
  short8 w1f[2];
  short8 bfr[2][4];
#pragma unroll
  for (int jj = 0; jj < 2; ++jj) {
    const int c = (2 * w + jj) * 16 + n;
    short8 v = zero8;
    if (q == 0) v = *(const short8*)&W1s[(size_t)c * L_];
    w1f[jj] = v;
#pragma unroll
    for (int ks = 0; ks < 4; ++ks)
      bfr[jj][ks] = *(const short8*)&W2s[(size_t)c * H_ + ks * 32 + q * 8];
  }

  float qsum = 0.0f;
  __syncthreads();   // Zt ready

#pragma unroll 1
  for (int half = 0; half < 2; ++half) {
#pragma unroll 1
    for (int mi = 0; mi < 8; ++mi) {
      short8 zf = zero8;
      if (q == 0) zf = *(const short8*)&Zt[half * 128 + mi * 16 + n][0];
      float4v c0 = __builtin_amdgcn_mfma_f32_16x16x32_bf16(zf, w1f[0], (float4v){0.f,0.f,0.f,0.f}, 0, 0, 0);
      float4v c1 = __builtin_amdgcn_mfma_f32_16x16x32_bf16(zf, w1f[1], (float4v){0.f,0.f,0.f,0.f}, 0, 0, 0);
#pragma unroll
      for (int r = 0; r < 4; ++r) {
        float a0 = c0[r] + b12[0];
        float a1 = c1[r] + b12[1];
        float p0 = __expf(2.f * a0) + 1.f;
        float p1 = __expf(2.f * a1) + 1.f;
        float rj = __builtin_amdgcn_rcpf(p0 * p1);
        float h0 = 1.f - 2.f * p1 * rj;
        float h1 = 1.f - 2.f * p0 * rj;
        hS[mi * 16 + q * 4 + r][(2 * w) * 16 + n] = __float2bfloat16(h0);
        hS[mi * 16 + q * 4 + r][(2 * w + 1) * 16 + n] = __float2bfloat16(h1);
      }
    }
    __syncthreads();
#pragma unroll 1
    for (int mi = 0; mi < 8; ++mi) {
      short8 af[4];
#pragma unroll
      for (int ks = 0; ks < 4; ++ks)
        af[ks] = *(const short8*)&hS[mi * 16 + n][ks * 32 + q * 8];
      float4v acc0 = (float4v){0.f, 0.f, 0.f, 0.f};
      float4v acc1 = (float4v){0.f, 0.f, 0.f, 0.f};
#pragma unroll
      for (int ks = 0; ks < 4; ++ks) {
        acc0 = __builtin_amdgcn_mfma_f32_16x16x32_bf16(af[ks], bfr[0][ks], acc0, 0, 0, 0);
        acc1 = __builtin_amdgcn_mfma_f32_16x16x32_bf16(af[ks], bfr[1][ks], acc1, 0, 0, 0);
      }
#pragma unroll
      for (int r = 0; r < 4; ++r) {
        const int t = half * 128 + mi * 16 + q * 4 + r;
        const float2 xv = *(const float2*)(X + (((size_t)b << 8) + t) * D_ + d0);
        float diff0 = xv.x - (acc0[r] + b22[0]);
        float diff1 = xv.y - (acc1[r] + b22[1]);
        qsum += diff0 * diff0 * invr2[0] + diff1 * diff1 * invr2[1];
      }
    }
    __syncthreads();
  }

#pragma unroll
  for (int off = 32; off >= 1; off >>= 1) qsum += __shfl_xor(qsum, off);
  if (lane == 0) redbuf[w] = qsum;
  __syncthreads();
  if (tid == 0) {
    float Q = redbuf[0] + redbuf[1] + redbuf[2] + redbuf[3];
    float log_norm = 0.5f * (sLR + (float)D_ * 1.8378770664093453f);
    ll[bs] = -0.5f * Q - (float)T_ * log_norm;
  }
}

// ---------------------------------------------------------------------------
// Final: nll[b] = -(logsumexp_s(ll) - log S). One wave per b.
// ---------------------------------------------------------------------------
__global__ __launch_bounds__(64) void k_lse(
    const float* __restrict__ ll, float* __restrict__ out)
{
  const int b = blockIdx.x;
  const int s = threadIdx.x;
  float v = ll[b * 64 + s];
  float m = v;
#pragma unroll
  for (int off = 32; off >= 1; off >>= 1) m = fmaxf(m, __shfl_xor(m, off));
  float e = __expf(v - m);
#pragma unroll
  for (int off = 32; off >= 1; off >>= 1) e += __shfl_xor(e, off);
  if (s == 0) out[b] = -(m + __logf(e) - 4.1588830833596715f);
}

extern "C" void kernel_launch(void* const* d_in, const int* in_sizes, int n_in,
                              void* d_out, int out_size, void* d_ws, size_t ws_size,
                              hipStream_t stream) {
  const float* X        = (const float*)d_in[0];
  const float* times    = (const float*)d_in[1];
  const float* log_taus = (const float*)d_in[2];
  const float* log_R    = (const float*)d_in[3];
  const float* W1       = (const float*)d_in[4];
  const float* b1       = (const float*)d_in[5];
  const float* W2       = (const float*)d_in[6];
  const float* b2       = (const float*)d_in[7];
  const float* eps      = (const float*)d_in[8];
  float* out = (float*)d_out;

  char* ws = (char*)d_ws;
  __hip_bfloat16* Lcbf = (__hip_bfloat16*)(ws);                // 1 MiB bf16 [L][T][T]
  __hip_bfloat16* Zg   = (__hip_bfloat16*)(ws + 1048576);      // 8 MiB bf16 [BS][T][L]
  float* ll            = (float*)(ws + 9437184);               // 8 KiB
  __hip_bfloat16* W2T  = (__hip_bfloat16*)(ws + 9445376);      // 32 KiB
  __hip_bfloat16* W1T  = (__hip_bfloat16*)(ws + 9478144);      // 2 KiB

  hipLaunchKernelGGL(k_chol_prep, dim3(72),   dim3(64),  0, stream,
                     times, log_taus, Lcbf, W1, W2, W1T, W2T);
  hipLaunchKernelGGL(k_zgemm,     dim3(512),  dim3(256), 0, stream, eps, Lcbf, Zg);
  hipLaunchKernelGGL(k_decode,    dim3(2048), dim3(256), 0, stream,
                     X, Zg, W1T, b1, W2T, b2, log_R, ll);
  hipLaunchKernelGGL(k_lse,       dim3(32),   dim3(64),  0, stream, ll, out);
}

// Round 14
// 174.437 us; speedup vs baseline: 1.3266x; 1.0096x over previous
//
#include <hip/hip_runtime.h>
#include <hip/hip_bf16.h>
#include <math.h>

#define B_ 32
#define S_ 64
#define T_ 256
#define L_ 8
#define D_ 128
#define H_ 128

typedef __attribute__((ext_vector_type(8))) short short8;
typedef __attribute__((ext_vector_type(4))) short short4v;
typedef __attribute__((ext_vector_type(4))) float float4v;

__device__ __forceinline__ short f2bf(float x) {
  __hip_bfloat16 h = __float2bfloat16(x);
  return *reinterpret_cast<short*>(&h);
}

__device__ __forceinline__ float rdlane(float x, int sl) {
  return __int_as_float(__builtin_amdgcn_readlane(__float_as_int(x), sl));
}
__device__ __forceinline__ float dpp_shr1(float x, float tailv) {
  int r = __builtin_amdgcn_update_dpp(__float_as_int(tailv), __float_as_int(x),
                                      0x138, 0xF, 0xF, false);
  return __int_as_float(r);
}

// ---------------------------------------------------------------------------
// Stage A (+prep merged): blocks 0-7: Toeplitz-Schur Cholesky (readlane +
// DPP wave_shr serial chain; LDS panel flushed as coalesced rows covering
// exactly zgemm's triangular read region). Blocks 8-71: weight conversion
// W1T[h][l], W2T[c][h] (c=nt*16+n <-> d=n*8+nt).
// ---------------------------------------------------------------------------
__global__ __launch_bounds__(64) void k_chol_prep(
    const float* __restrict__ times, const float* __restrict__ log_taus,
    __hip_bfloat16* __restrict__ Lcbf_,
    const float* __restrict__ W1, const float* __restrict__ W2,
    __hip_bfloat16* __restrict__ W1T, __hip_bfloat16* __restrict__ W2T)
{
  __shared__ short panel[256][68];
  const int bi = blockIdx.x;
  const int j = threadIdx.x;

  if (bi >= 8) {
    const int base = (bi - 8) * 64 + j;          // 0..4095
    for (int idx = base; idx < H_ * D_; idx += 4096) {
      const int cc = idx >> 7, h = idx & 127;
      const int n = cc & 15, nt = cc >> 4;
      const int d = n * 8 + nt;
      W2T[(size_t)cc * H_ + h] = __float2bfloat16(W2[(size_t)h * D_ + d]);
    }
    for (int idx = base; idx < L_ * H_; idx += 4096) {
      const int li = idx >> 7, h = idx & 127;
      W1T[(size_t)h * L_ + li] = __float2bfloat16(W1[idx]);
    }
    return;
  }

  const int l = bi;
  short* Lbf = (short*)Lcbf_ + (size_t)l * T_ * T_;

  const float tau = expf(log_taus[l]);
  const float inv2tau2 = 0.5f / (tau * tau);
  const float sig2 = 0.999f * 0.999f;
  const float t0 = times[0];

  const float c0 = sig2 + 1e-4f;
  const float isc0 = 1.0f / sqrtf(c0);

  float u[4], v[4];
#pragma unroll
  for (int c = 0; c < 4; ++c) {
    const int d = c * 64 + j;
    const float dt = times[d] - t0;
    float cv = sig2 * __expf(-dt * dt * inv2tau2);
    if (d == 0) cv = c0;
    u[c] = cv * isc0;
    v[c] = (d == 0) ? 0.0f : u[c];
  }

#pragma unroll
  for (int p = 0; p < 4; ++p) {
    for (int kk = 0; kk < 64; ++kk) {
      const float uk = rdlane(u[p], kk);
      const float vk = rdlane(v[p], kk);
      const float rho = vk * __builtin_amdgcn_rcpf(uk);
      const float om = fmaxf(1.0f - rho * rho, 1e-12f);
      const float s = __builtin_amdgcn_rsqf(om);
      const float sr = s * rho;

      float up[4];
#pragma unroll
      for (int c = 0; c < 4; ++c) {
        if (c >= p) {
          const float uc = u[c], vc = v[c];
          up[c] = s * uc - sr * vc;
          v[c]  = s * vc - sr * uc;
          const float val = (c > p || j >= kk) ? up[c] : 0.0f;
          panel[(c - p) * 64 + j][kk] = f2bf(val);
        }
      }
#pragma unroll
      for (int c = 3; c >= 0; --c) {
        if (c >= p) {
          const float tail = (c > p) ? rdlane(up[c - 1], 63) : 0.0f;
          u[c] = dpp_shr1(up[c], tail);
        }
      }
    }
    __syncthreads();
    const int rpt = 256 - 64 * p;
    const int rsub = j >> 4, cp = (j & 15) * 4;
    for (int i0 = 0; i0 < rpt; i0 += 4) {
      const int pr = i0 + rsub;
      short4v vv = *(const short4v*)&panel[pr][cp];
      *(short4v*)&Lbf[((size_t)(p * 64 + pr) << 8) + p * 64 + cp] = vv;
    }
    __syncthreads();
  }
}

// ---------------------------------------------------------------------------
// Stage B: z GEMM via bf16 MFMA — R10 grid (256 blocks, full-column waves,
// 64-wide bs tiles for 4x L-read amortization) + COALESCED staging: wave w
// stages rows [16w,16w+16), lane = float4 column -> each global load is a
// perfect 1 KB wave transaction. Wave w owns u in [64w,64w+64) =>
// K <= 64(w+1) (triangular skip). Output Z[bs][t][l] bf16.
// ---------------------------------------------------------------------------
__global__ __launch_bounds__(256) void k_zgemm(
    const float* __restrict__ eps, const __hip_bfloat16* __restrict__ Lcbf_,
    __hip_bfloat16* __restrict__ Zg)
{
  __shared__ __align__(16) short E[64][264];
  const int bi = blockIdx.x;
  const int l = bi & 7, bs0 = (bi >> 3) * 64;
  const int tid = threadIdx.x, w = tid >> 6, lane = tid & 63;
  const int n = lane & 15, q = lane >> 4;
  const short* Lb = (const short*)Lcbf_ + (size_t)l * T_ * T_;

  // coalesced staging: wave w -> rows 16w..16w+15, lane -> float4 col
#pragma unroll
  for (int i = 0; i < 16; ++i) {
    const int row = w * 16 + i;
    float4v f = *(const float4v*)(eps + ((size_t)(bs0 + row) * L_ + l) * T_ + lane * 4);
    short4v o;
#pragma unroll
    for (int jj = 0; jj < 4; ++jj) o[jj] = f2bf(f[jj]);
    *(short4v*)&E[row][lane * 4] = o;
  }
  __syncthreads();

  float4v acc[4][4];
#pragma unroll
  for (int mt = 0; mt < 4; ++mt)
#pragma unroll
    for (int nt = 0; nt < 4; ++nt) acc[mt][nt] = (float4v){0.f, 0.f, 0.f, 0.f};

  const int kend = (w + 1) * 64;
  for (int k0 = 0; k0 < kend; k0 += 32) {
    short8 bfrg[4], afr[4];
#pragma unroll
    for (int nt = 0; nt < 4; ++nt)
      bfrg[nt] = *(const short8*)&E[nt * 16 + n][k0 + q * 8];
#pragma unroll
    for (int mt = 0; mt < 4; ++mt) {
      const int u = w * 64 + mt * 16 + n;
      afr[mt] = *(const short8*)&Lb[((size_t)u << 8) + k0 + q * 8];
    }
#pragma unroll
    for (int mt = 0; mt < 4; ++mt)
#pragma unroll
      for (int nt = 0; nt < 4; ++nt)
        acc[mt][nt] = __builtin_amdgcn_mfma_f32_16x16x32_bf16(afr[mt], bfrg[nt], acc[mt][nt], 0, 0, 0);
  }
#pragma unroll
  for (int mt = 0; mt < 4; ++mt)
#pragma unroll
    for (int nt = 0; nt < 4; ++nt) {
      const int bs = bs0 + nt * 16 + n;
#pragma unroll
      for (int r = 0; r < 4; ++r) {
        const int u = w * 64 + mt * 16 + q * 4 + r;
        Zg[((size_t)bs << 11) + (u << 3) + l] = __float2bfloat16(acc[mt][nt][r]);
      }
    }
}

// ---------------------------------------------------------------------------
// Stages C-F fused — R10 champion + X-load hoisting: the 4 epilogue float2
// loads per mi are issued BEFORE the ds_read/MFMA chain so their ~200-cyc L2
// latency overlaps the matrix work instead of stalling the epilogue.
// One block per (b,s), D-columns across waves, hS[128][136] halves,
// launch_bounds (256,4), unroll 1 (no spill), joint-rcp tanh pairs.
// ---------------------------------------------------------------------------
__global__ __launch_bounds__(256, 4) void k_decode(
    const float* __restrict__ X, const __hip_bfloat16* __restrict__ Zg,
    const __hip_bfloat16* __restrict__ W1T, const float* __restrict__ b1,
    const __hip_bfloat16* __restrict__ W2T, const float* __restrict__ b2,
    const float* __restrict__ log_R, float* __restrict__ ll)
{
  __shared__ __align__(16) short Zt[256][8];
  __shared__ __align__(16) __hip_bfloat16 hS[128][136];
  __shared__ float redbuf[4];

  const int bs = blockIdx.x;
  const int b = bs >> 6;
  const int tid = threadIdx.x;
  const int w = tid >> 6, lane = tid & 63;
  const int n = lane & 15, q = lane >> 4;
  const short* Zs = (const short*)Zg;
  const short* W1s = (const short*)W1T;
  const short* W2s = (const short*)W2T;

  *(short8*)&Zt[tid][0] = *(const short8*)&Zs[((size_t)bs << 11) + tid * 8];

  float sLR = log_R[lane] + log_R[lane + 64];
#pragma unroll
  for (int off = 32; off >= 1; off >>= 1) sLR += __shfl_xor(sLR, off);

  const int d0 = n * 8 + 2 * w;
  float invr2[2], b22[2], b12[2];
#pragma unroll
  for (int jj = 0; jj < 2; ++jj) {
    invr2[jj] = expf(-log_R[d0 + jj]);
    b22[jj] = b2[d0 + jj];
    b12[jj] = b1[(2 * w + jj) * 16 + n];
  }

  const short8 zero8 = {0, 0, 0, 0, 0, 0, 0, 0};
  short8 w1f[2];
  short8 bfr[2][4];
#pragma unroll
  for (int jj = 0; jj < 2; ++jj) {
    const int c = (2 * w + jj) * 16 + n;
    short8 v = zero8;
    if (q == 0) v = *(const short8*)&W1s[(size_t)c * L_];
    w1f[jj] = v;
#pragma unroll
    for (int ks = 0; ks < 4; ++ks)
      bfr[jj][ks] = *(const short8*)&W2s[(size_t)c * H_ + ks * 32 + q * 8];
  }

  float qsum = 0.0f;
  __syncthreads();   // Zt ready

#pragma unroll 1
  for (int half = 0; half < 2; ++half) {
#pragma unroll 1
    for (int mi = 0; mi < 8; ++mi) {
      short8 zf = zero8;
      if (q == 0) zf = *(const short8*)&Zt[half * 128 + mi * 16 + n][0];
      float4v c0 = __builtin_amdgcn_mfma_f32_16x16x32_bf16(zf, w1f[0], (float4v){0.f,0.f,0.f,0.f}, 0, 0, 0);
      float4v c1 = __builtin_amdgcn_mfma_f32_16x16x32_bf16(zf, w1f[1], (float4v){0.f,0.f,0.f,0.f}, 0, 0, 0);
#pragma unroll
      for (int r = 0; r < 4; ++r) {
        float a0 = c0[r] + b12[0];
        float a1 = c1[r] + b12[1];
        float p0 = __expf(2.f * a0) + 1.f;
        float p1 = __expf(2.f * a1) + 1.f;
        float rj = __builtin_amdgcn_rcpf(p0 * p1);
        float h0 = 1.f - 2.f * p1 * rj;
        float h1 = 1.f - 2.f * p0 * rj;
        hS[mi * 16 + q * 4 + r][(2 * w) * 16 + n] = __float2bfloat16(h0);
        hS[mi * 16 + q * 4 + r][(2 * w + 1) * 16 + n] = __float2bfloat16(h1);
      }
    }
    __syncthreads();
#pragma unroll 1
    for (int mi = 0; mi < 8; ++mi) {
      // hoisted X loads: issue early, wait only in the epilogue
      float2 xv4[4];
#pragma unroll
      for (int r = 0; r < 4; ++r) {
        const int t = half * 128 + mi * 16 + q * 4 + r;
        xv4[r] = *(const float2*)(X + (((size_t)b << 8) + t) * D_ + d0);
      }
      short8 af[4];
#pragma unroll
      for (int ks = 0; ks < 4; ++ks)
        af[ks] = *(const short8*)&hS[mi * 16 + n][ks * 32 + q * 8];
      float4v acc0 = (float4v){0.f, 0.f, 0.f, 0.f};
      float4v acc1 = (float4v){0.f, 0.f, 0.f, 0.f};
#pragma unroll
      for (int ks = 0; ks < 4; ++ks) {
        acc0 = __builtin_amdgcn_mfma_f32_16x16x32_bf16(af[ks], bfr[0][ks], acc0, 0, 0, 0);
        acc1 = __builtin_amdgcn_mfma_f32_16x16x32_bf16(af[ks], bfr[1][ks], acc1, 0, 0, 0);
      }
#pragma unroll
      for (int r = 0; r < 4; ++r) {
        float diff0 = xv4[r].x - (acc0[r] + b22[0]);
        float diff1 = xv4[r].y - (acc1[r] + b22[1]);
        qsum += diff0 * diff0 * invr2[0] + diff1 * diff1 * invr2[1];
      }
    }
    __syncthreads();
  }

#pragma unroll
  for (int off = 32; off >= 1; off >>= 1) qsum += __shfl_xor(qsum, off);
  if (lane == 0) redbuf[w] = qsum;
  __syncthreads();
  if (tid == 0) {
    float Q = redbuf[0] + redbuf[1] + redbuf[2] + redbuf[3];
    float log_norm = 0.5f * (sLR + (float)D_ * 1.8378770664093453f);
    ll[bs] = -0.5f * Q - (float)T_ * log_norm;
  }
}

// ---------------------------------------------------------------------------
// Final: nll[b] = -(logsumexp_s(ll) - log S). One wave per b.
// ---------------------------------------------------------------------------
__global__ __launch_bounds__(64) void k_lse(
    const float* __restrict__ ll, float* __restrict__ out)
{
  const int b = blockIdx.x;
  const int s = threadIdx.x;
  float v = ll[b * 64 + s];
  float m = v;
#pragma unroll
  for (int off = 32; off >= 1; off >>= 1) m = fmaxf(m, __shfl_xor(m, off));
  float e = __expf(v - m);
#pragma unroll
  for (int off = 32; off >= 1; off >>= 1) e += __shfl_xor(e, off);
  if (s == 0) out[b] = -(m + __logf(e) - 4.1588830833596715f);
}

extern "C" void kernel_launch(void* const* d_in, const int* in_sizes, int n_in,
                              void* d_out, int out_size, void* d_ws, size_t ws_size,
                              hipStream_t stream) {
  const float* X        = (const float*)d_in[0];
  const float* times    = (const float*)d_in[1];
  const float* log_taus = (const float*)d_in[2];
  const float* log_R    = (const float*)d_in[3];
  const float* W1       = (const float*)d_in[4];
  const float* b1       = (const float*)d_in[5];
  const float* W2       = (const float*)d_in[6];
  const float* b2       = (const float*)d_in[7];
  const float* eps      = (const float*)d_in[8];
  float* out = (float*)d_out;

  char* ws = (char*)d_ws;
  __hip_bfloat16* Lcbf = (__hip_bfloat16*)(ws);                // 1 MiB bf16 [L][T][T]
  __hip_bfloat16* Zg   = (__hip_bfloat16*)(ws + 1048576);      // 8 MiB bf16 [BS][T][L]
  float* ll            = (float*)(ws + 9437184);               // 8 KiB
  __hip_bfloat16* W2T  = (__hip_bfloat16*)(ws + 9445376);      // 32 KiB
  __hip_bfloat16* W1T  = (__hip_bfloat16*)(ws + 9478144);      // 2 KiB

  hipLaunchKernelGGL(k_chol_prep, dim3(72),   dim3(64),  0, stream,
                     times, log_taus, Lcbf, W1, W2, W1T, W2T);
  hipLaunchKernelGGL(k_zgemm,     dim3(256),  dim3(256), 0, stream, eps, Lcbf, Zg);
  hipLaunchKernelGGL(k_decode,    dim3(2048), dim3(256), 0, stream,
                     X, Zg, W1T, b1, W2T, b2, log_R, ll);
  hipLaunchKernelGGL(k_lse,       dim3(32),   dim3(64),  0, stream, ll, out);
}